// Round 3
// baseline (18.682 us; speedup 1.0000x reference)
//
#include <hip/hip_runtime.h>
#include <hip/hip_bf16.h>

// TrueQLACI_Quantum: exact closed form.
//
// The quantum subcircuit (CNOT fan-in, RZ(theta_j), CNOT fan-out, repeated
// over 15 keys) is diagonal in the computational basis. Wire 8 starts in |0>;
// the conditional swaps + diagonal phase compose to a pure per-component
// phase, so the |1> amplitude stays exactly 0 and each of the 16 branch
// amplitudes keeps modulus 0.25. Hence <Z_8> = 16 * 0.0625 = 1.0 for EVERY
// sample, independent of tokens/q/k.
//
// reference(...) = 1.0 @ W_out.T + b_out  ->  out[b][i] = W_out[i] + b_out[i]
// broadcast over B = 131072 rows: a 16 MiB constant-row store.
//
// This version: 2048 WGs x 256 threads, 2 float4 stores per thread.
// Store indices i and i+256 share the same column group (256 % 8 == 0),
// so one w+b add feeds both stores. No bounds check (exact division).

__global__ __launch_bounds__(256) void qlaci_broadcast(
        const float4* __restrict__ W_out,  // [8] float4 (32 floats)
        const float4* __restrict__ b_out,  // [8] float4
        float4* __restrict__ out) {        // [1048576] float4
    const int i = blockIdx.x * 512 + threadIdx.x;  // block covers 512 float4s
    const int c = i & 7;                           // column group (same for i+256)
    const float4 w = W_out[c];
    const float4 b = b_out[c];
    const float4 v = make_float4(w.x + b.x, w.y + b.y, w.z + b.z, w.w + b.w);
    out[i]       = v;
    out[i + 256] = v;
}

extern "C" void kernel_launch(void* const* d_in, const int* in_sizes, int n_in,
                              void* d_out, int out_size, void* d_ws, size_t ws_size,
                              hipStream_t stream) {
    // setup_inputs order: tokens, W_emb, b_emb, W_q, b_q, W_k, b_k, W_out, b_out
    const float4* W_out = (const float4*)d_in[7];  // 32 floats
    const float4* b_out = (const float4*)d_in[8];  // 32 floats
    float4* out = (float4*)d_out;

    // out_size = 4194304 floats = 1048576 float4 = 2048 blocks * 256 thr * 2
    const int grid = (out_size / 4) / 512;
    qlaci_broadcast<<<grid, 256, 0, stream>>>(W_out, b_out, out);
}

// Round 4
// 11.242 us; speedup vs baseline: 1.6618x; 1.6618x over previous
//
#include <hip/hip_runtime.h>
#include <hip/hip_bf16.h>

// TrueQLACI_Quantum: exact closed form.
//
// The quantum subcircuit (CNOT fan-in, RZ(theta_j), CNOT fan-out, repeated
// over 15 keys) is diagonal in the computational basis. Wire 8 starts in |0>;
// the conditional swaps + diagonal phase compose to a pure per-component
// phase, so the |1> amplitude stays exactly 0 and each of the 16 branch
// amplitudes keeps modulus 0.25. Hence <Z_8> = 16 * 0.0625 = 1.0 for EVERY
// sample, independent of tokens/q/k.
//
// reference(...) = 1.0 @ W_out.T + b_out  ->  out[b][i] = W_out[i] + b_out[i]
// broadcast over B = 131072 rows: a 16 MiB constant-row store.
//
// Round-2 configuration (best measured: 11.2 us): 4096 WGs x 256 threads,
// one float4 store per thread, no LDS, no barrier, no loop. Round 3's
// 2048-WG/2-store variant measured 18.7 us -> reverted.

__global__ __launch_bounds__(256) void qlaci_broadcast(
        const float4* __restrict__ W_out,  // [8] float4 (32 floats)
        const float4* __restrict__ b_out,  // [8] float4
        float4* __restrict__ out,          // [B*32/4] float4
        int n4) {
    const int i = blockIdx.x * blockDim.x + threadIdx.x;
    if (i >= n4) return;
    const int c = i & 7;                   // column group within the 32-wide row
    const float4 w = W_out[c];
    const float4 b = b_out[c];
    out[i] = make_float4(w.x + b.x, w.y + b.y, w.z + b.z, w.w + b.w);
}

extern "C" void kernel_launch(void* const* d_in, const int* in_sizes, int n_in,
                              void* d_out, int out_size, void* d_ws, size_t ws_size,
                              hipStream_t stream) {
    // setup_inputs order: tokens, W_emb, b_emb, W_q, b_q, W_k, b_k, W_out, b_out
    const float4* W_out = (const float4*)d_in[7];  // 32 floats
    const float4* b_out = (const float4*)d_in[8];  // 32 floats
    float4* out = (float4*)d_out;

    const int n4 = out_size / 4;                   // 4194304 / 4 = 1048576
    const int block = 256;
    const int grid = (n4 + block - 1) / block;     // 4096: one store per thread

    qlaci_broadcast<<<grid, block, 0, stream>>>(W_out, b_out, out, n4);
}